// Round 3
// baseline (587.452 us; speedup 1.0000x reference)
//
#include <hip/hip_runtime.h>

typedef _Float16 half8 __attribute__((ext_vector_type(8)));
typedef float f32x4 __attribute__((ext_vector_type(4)));

// Problem constants (b=16, h=w=56, c=512, nh=8, dh=64, split=7, IDX=0)
constexpr int Bn  = 16;
constexpr int Wn  = 56;   // image width (and height)
constexpr int Cc  = 512;
constexpr int DH  = 64;
constexpr int WSP = 7;    // w_sp
constexpr long TS = (long)Bn * 56 * 56 * Cc;  // per-tensor stride in qkv

#define VT_S 424   // V^T LDS row stride in halfs (padded from 416 for banks)
#define PS_S 40    // P scratch row stride in halfs (padded from 32 for banks)

// One block per (window, head): blockIdx.x = win*8 + head, win = b*8 + ww.
// 8 waves; each wave owns 16-row Q tiles (25 tiles cover 392 rows padded to 400).
__global__ __launch_bounds__(512, 2)
void lepe_attn(const float* __restrict__ qkv,
               const float* __restrict__ convw,
               const float* __restrict__ convb,
               float* __restrict__ out)
{
    __shared__ __align__(16) _Float16 Klds[400 * 64];      // swizzled: byte = row*128 + (col ^ ((row&7)<<4))
    __shared__ __align__(16) _Float16 VT[64 * VT_S];       // V^T: [d][token], tokens 0..415 (>=392 zero)
    __shared__ __align__(16) _Float16 Pscr[8 * 16 * PS_S]; // per-wave P transpose scratch
    __shared__ float Wlds[576];                            // conv weights for this head: [d][9]
    __shared__ float Blds[64];                             // conv bias for this head

    const int tid  = threadIdx.x;
    const int head = blockIdx.x & 7;
    const int win  = blockIdx.x >> 3;
    const int bb   = win >> 3;
    const int ww   = win & 7;

    const float* qbase = qkv + (long)bb * 56 * 56 * Cc + head * DH;
    const float* kbase = qbase + TS;
    const float* vbase = qbase + 2 * TS;

    char* Kb = (char*)Klds;

    // ---------------- stage K (f16, XOR-swizzled 16B units) ----------------
    {
        int part = tid & 3;  // 16-channel chunk within row
        #pragma unroll
        for (int p = 0; p < 4; ++p) {
            int row = p * 128 + (tid >> 2);
            if (row < 400) {
                half8 lo, hi;
                if (row < 392) {
                    int r = row / 7, cw = row - r * 7;
                    const float4* s4 = (const float4*)(kbase + (long)(r * Wn + ww * WSP + cw) * Cc + part * 16);
                    float4 a0 = s4[0], a1 = s4[1], a2 = s4[2], a3 = s4[3];
                    lo[0]=(_Float16)a0.x; lo[1]=(_Float16)a0.y; lo[2]=(_Float16)a0.z; lo[3]=(_Float16)a0.w;
                    lo[4]=(_Float16)a1.x; lo[5]=(_Float16)a1.y; lo[6]=(_Float16)a1.z; lo[7]=(_Float16)a1.w;
                    hi[0]=(_Float16)a2.x; hi[1]=(_Float16)a2.y; hi[2]=(_Float16)a2.z; hi[3]=(_Float16)a2.w;
                    hi[4]=(_Float16)a3.x; hi[5]=(_Float16)a3.y; hi[6]=(_Float16)a3.z; hi[7]=(_Float16)a3.w;
                } else {
                    #pragma unroll
                    for (int i = 0; i < 8; i++) { lo[i] = (_Float16)0.f; hi[i] = (_Float16)0.f; }
                }
                int sw = (row & 7) << 4;
                *(half8*)(Kb + row * 128 + ((part * 32) ^ sw))      = lo;
                *(half8*)(Kb + row * 128 + ((part * 32 + 16) ^ sw)) = hi;
            }
        }
    }

    // ---------------- stage V^T (transpose during store) ----------------
    #pragma unroll
    for (int p = 0; p < 13; ++p) {
        int idx = p * 512 + tid;       // 13*512 = 6656 = 416 tokens * 16 chunks
        int tk = idx >> 4, dq = idx & 15;
        float4 vv = make_float4(0.f, 0.f, 0.f, 0.f);
        if (tk < 392) {
            int r = tk / 7, cw = tk - r * 7;
            vv = *(const float4*)(vbase + (long)(r * Wn + ww * WSP + cw) * Cc + dq * 4);
        }
        int d0 = dq * 4;
        VT[(d0 + 0) * VT_S + tk] = (_Float16)vv.x;
        VT[(d0 + 1) * VT_S + tk] = (_Float16)vv.y;
        VT[(d0 + 2) * VT_S + tk] = (_Float16)vv.z;
        VT[(d0 + 3) * VT_S + tk] = (_Float16)vv.w;
    }

    // ---------------- stage conv weights/bias for this head ----------------
    // (576 weights, 512 threads: all threads load one, first 64 load the tail)
    Wlds[tid] = convw[head * 576 + tid];
    if (tid < 64) {
        Wlds[512 + tid] = convw[head * 576 + 512 + tid];
        Blds[tid] = convb[head * DH + tid];
    }

    __syncthreads();

    const int wv = tid >> 6;
    const int lr = tid & 15;          // lane & 15
    const int lg = (tid >> 4) & 3;    // lane >> 4
    _Float16* pw = Pscr + wv * (16 * PS_S);
    const char* vtb = (const char*)VT;

    for (int qt = wv; qt < 25; qt += 8) {
        // ---- Q fragment (A operand: row = lane&15, k = (lane>>4)*8 + j), scaled by dh^-0.5 = 0.125
        half8 a0, a1;
        {
            int tq = qt * 16 + lr; if (tq > 391) tq = 391;  // clamp padded rows (never stored)
            int r = tq / 7, cw = tq - r * 7;
            const float* qp = qbase + (long)(r * Wn + ww * WSP + cw) * Cc + lg * 8;
            float4 x0 = *(const float4*)qp;
            float4 x1 = *(const float4*)(qp + 4);
            float4 y0 = *(const float4*)(qp + 32);
            float4 y1 = *(const float4*)(qp + 36);
            a0[0]=(_Float16)(x0.x*0.125f); a0[1]=(_Float16)(x0.y*0.125f);
            a0[2]=(_Float16)(x0.z*0.125f); a0[3]=(_Float16)(x0.w*0.125f);
            a0[4]=(_Float16)(x1.x*0.125f); a0[5]=(_Float16)(x1.y*0.125f);
            a0[6]=(_Float16)(x1.z*0.125f); a0[7]=(_Float16)(x1.w*0.125f);
            a1[0]=(_Float16)(y0.x*0.125f); a1[1]=(_Float16)(y0.y*0.125f);
            a1[2]=(_Float16)(y0.z*0.125f); a1[3]=(_Float16)(y0.w*0.125f);
            a1[4]=(_Float16)(y1.x*0.125f); a1[5]=(_Float16)(y1.y*0.125f);
            a1[6]=(_Float16)(y1.z*0.125f); a1[7]=(_Float16)(y1.w*0.125f);
        }

        // ---- S = Q K^T : 25 col-tiles, acc D[m=(l>>4)*4+j][n=l&15]
        f32x4 s[25];
        #pragma unroll
        for (int t = 0; t < 25; t++) s[t] = (f32x4){0.f, 0.f, 0.f, 0.f};
        #pragma unroll
        for (int t = 0; t < 25; t++) {
            int row = t * 16 + lr;
            int sw = (row & 7) << 4;
            half8 b0 = *(const half8*)(Kb + row * 128 + ((lg * 16) ^ sw));
            half8 b1 = *(const half8*)(Kb + row * 128 + ((64 + lg * 16) ^ sw));
            s[t] = __builtin_amdgcn_mfma_f32_16x16x32_f16(a0, b0, s[t], 0, 0, 0);
            s[t] = __builtin_amdgcn_mfma_f32_16x16x32_f16(a1, b1, s[t], 0, 0, 0);
        }

        // mask padded K columns 392..399 (tile 24, cols lane&15 >= 8)
        if (lr >= 8) { s[24][0] = -1e30f; s[24][1] = -1e30f; s[24][2] = -1e30f; s[24][3] = -1e30f; }

        // ---- softmax per q-row (row j held by 16 lanes sharing lg): unnormalized exp, row sums
        float su[4];
        #pragma unroll
        for (int j = 0; j < 4; j++) {
            float m = s[0][j];
            #pragma unroll
            for (int t = 1; t < 25; t++) m = fmaxf(m, s[t][j]);
            m = fmaxf(m, __shfl_xor(m, 1));
            m = fmaxf(m, __shfl_xor(m, 2));
            m = fmaxf(m, __shfl_xor(m, 4));
            m = fmaxf(m, __shfl_xor(m, 8));
            float sm = 0.f;
            #pragma unroll
            for (int t = 0; t < 25; t++) { float pp = __expf(s[t][j] - m); s[t][j] = pp; sm += pp; }
            sm += __shfl_xor(sm, 1);
            sm += __shfl_xor(sm, 2);
            sm += __shfl_xor(sm, 4);
            sm += __shfl_xor(sm, 8);
            su[j] = sm;
        }

        // ---- O = P V : 13 k-chunks of 32 tokens; P transposed via wave-private LDS scratch
        f32x4 o[4];
        #pragma unroll
        for (int dt = 0; dt < 4; dt++) o[dt] = (f32x4){0.f, 0.f, 0.f, 0.f};
        #pragma unroll
        for (int kc = 0; kc < 13; kc++) {
            #pragma unroll
            for (int j = 0; j < 4; j++) {
                int rw = lg * 4 + j;
                pw[rw * PS_S + lr]      = (_Float16)s[2 * kc][j];
                pw[rw * PS_S + 16 + lr] = (kc < 12) ? (_Float16)s[2 * kc + 1][j] : (_Float16)0.f;
            }
            __builtin_amdgcn_wave_barrier();   // keep write->read order (per-wave LDS, in-order DS unit)
            half8 pf = *(const half8*)((const char*)pw + lr * (2 * PS_S) + lg * 16);
            #pragma unroll
            for (int dt = 0; dt < 4; dt++) {
                half8 vf = *(const half8*)(vtb + (dt * 16 + lr) * (2 * VT_S) + kc * 64 + lg * 16);
                o[dt] = __builtin_amdgcn_mfma_f32_16x16x32_f16(pf, vf, o[dt], 0, 0, 0);
            }
        }

        // ---- epilogue: LePE depthwise 3x3 (window-local SAME pad) + bias + normalize + store
        #pragma unroll
        for (int j = 0; j < 4; j++) {
            int tokj = qt * 16 + lg * 4 + j;
            if (tokj >= 392) continue;
            float rinv = 1.0f / su[j];
            int rr = tokj / 7, cc = tokj - rr * 7;
            float* op = out + ((long)bb * 56 * 56 + rr * Wn + ww * WSP + cc) * Cc + head * DH;
            #pragma unroll
            for (int dt = 0; dt < 4; dt++) {
                int d = dt * 16 + lr;
                float lep = Blds[d];
                #pragma unroll
                for (int dr = -1; dr <= 1; dr++) {
                    if ((unsigned)(rr + dr) >= 56u) continue;
                    #pragma unroll
                    for (int dc = -1; dc <= 1; dc++) {
                        if ((unsigned)(cc + dc) >= 7u) continue;
                        int tp = tokj + dr * 7 + dc;
                        lep += Wlds[d * 9 + (dr + 1) * 3 + (dc + 1)] * (float)VT[d * VT_S + tp];
                    }
                }
                op[d] = o[dt][j] * rinv + lep;
            }
        }
    }
}

extern "C" void kernel_launch(void* const* d_in, const int* in_sizes, int n_in,
                              void* d_out, int out_size, void* d_ws, size_t ws_size,
                              hipStream_t stream) {
    const float* qkv = (const float*)d_in[0];
    const float* cw  = (const float*)d_in[1];
    const float* cb  = (const float*)d_in[2];
    float* out = (float*)d_out;
    // 128 windows * 8 heads = 1024 blocks, 512 threads (8 waves)
    lepe_attn<<<dim3(1024), dim3(512), 0, stream>>>(qkv, cw, cb, out);
}